// Round 1
// baseline (707.979 us; speedup 1.0000x reference)
//
#include <hip/hip_runtime.h>
#include <stdint.h>

typedef float f32x4 __attribute__((ext_vector_type(4)));
typedef short bf16x8 __attribute__((ext_vector_type(8)));

#define AS1 __attribute__((address_space(1)))
#define AS3 __attribute__((address_space(3)))

#define NB 32
#define NS 2048
#define ND 1024
#define NU 1024
#define NM (NB * NS)  // 65536 rows

// async 16B global->LDS (gfx950). LDS dest = wave-uniform base + lane*16.
__device__ __forceinline__ void glds16(const void* g, void* l) {
  __builtin_amdgcn_global_load_lds((const AS1 uint32_t*)g, (AS3 uint32_t*)l, 16, 0, 0);
}

__device__ __forceinline__ unsigned short bf16_rne(float f) {
  uint32_t u = __float_as_uint(f);
  u += 0x7fffu + ((u >> 16) & 1u);
  return (unsigned short)(u >> 16);
}

// (bf16_trunc(hi) << 16) | bf16_trunc(lo) in one v_perm_b32
__device__ __forceinline__ uint32_t pack_bf16_trunc(float lo, float hi) {
  return __builtin_amdgcn_perm(__float_as_uint(hi), __float_as_uint(lo), 0x07060302u);
}

__device__ __forceinline__ float fast_tanh(float x) {
  float e = __expf(2.0f * x);          // x->+inf: e=inf -> 1 ; x->-inf: e=0 -> -1
  return 1.0f - 2.0f / (e + 1.0f);
}

// ---------------- W1[k][u] fp32 -> W1T[u][k] bf16 (RNE) -------------------------
__global__ __launch_bounds__(256) void k_w1t(const float* __restrict__ W1,
                                             unsigned short* __restrict__ W1T) {
  __shared__ float t[64][65];  // +1 pad: conflict-free column reads
  const int n0 = blockIdx.x * 64, k0 = blockIdx.y * 64;
  const int tid = threadIdx.x;
  {
    const int r = tid >> 4, c4 = (tid & 15) << 2;
#pragma unroll
    for (int i = 0; i < 4; ++i) {
      f32x4 v = *(const f32x4*)(W1 + (size_t)(k0 + r + i * 16) * NU + n0 + c4);
      t[r + i * 16][c4 + 0] = v.x;
      t[r + i * 16][c4 + 1] = v.y;
      t[r + i * 16][c4 + 2] = v.z;
      t[r + i * 16][c4 + 3] = v.w;
    }
  }
  __syncthreads();
  const int rr = tid >> 2, cc = tid & 3;  // rr: local u-row, cc: 16-k chunk
  uint32_t o[8];
#pragma unroll
  for (int p = 0; p < 8; ++p) {
    float f0 = t[cc * 16 + 2 * p + 0][rr];
    float f1 = t[cc * 16 + 2 * p + 1][rr];
    o[p] = (uint32_t)bf16_rne(f0) | ((uint32_t)bf16_rne(f1) << 16);
  }
  unsigned short* dst = W1T + (size_t)(n0 + rr) * ND + k0 + cc * 16;
  *(uint4*)(dst + 0) = make_uint4(o[0], o[1], o[2], o[3]);
  *(uint4*)(dst + 8) = make_uint4(o[4], o[5], o[6], o[7]);
}

// ---------------- pq[b][u] = query[b]·W2[:,u] + b1[u] + b2[u] -------------------
__global__ __launch_bounds__(256) void k_pq(const float* __restrict__ query,
                                            const float* __restrict__ W2,
                                            const float* __restrict__ b1,
                                            const float* __restrict__ b2,
                                            float* __restrict__ pq) {
  const int u = blockIdx.x * 256 + threadIdx.x;
  const int b = blockIdx.y;
  const float* q = query + b * ND;
  float acc = b1[u] + b2[u];
#pragma unroll 8
  for (int k = 0; k < ND; ++k) acc = fmaf(q[k], W2[(size_t)k * NU + u], acc);
  pq[b * NU + u] = acc;
}

// ---------------- fused GEMM (values@W1) + tanh·V score reduction ---------------
// grid (8 n-chunks, 512 m-tiles), 256 threads (4 waves in 2x2), 128x128 tile, BK=32.
// A tile: fp32 in LDS [128 rows][8 x 16B chunks], chunk c stored at pos c^(m&7).
// B tile: bf16 in LDS [128 n-rows][4 x 16B chunks], chunk c at pos c^((n>>1)&3).
__global__ __launch_bounds__(256) void k_score(const float* __restrict__ values,
                                               const unsigned short* __restrict__ W1T,
                                               const float* __restrict__ pq,
                                               const float* __restrict__ V,
                                               float* __restrict__ score) {
  __shared__ f32x4 lds4[1536];  // 24 KiB: [0,16K)=A, [16K,24K)=B
  char* lds = (char*)lds4;

  const int tid = threadIdx.x;
  const int lane = tid & 63;
  const int w = tid >> 6;
  const int wr = w >> 1, wc = w & 1;      // wave 2x2, each 64x64
  const int quad = lane >> 4, l15 = lane & 15;

  const int nc = blockIdx.x;
  const int mt = blockIdx.y;
  const int m0 = mt * 128, n0 = nc * 128;

  // staging: A = 4 glds/wave (16KB tile), B = 2 glds/wave (8KB tile)
  const char* aG[4];
  uint32_t aL[4];
  {
    const int p = lane & 7, r3 = lane >> 3;
    const int ca = p ^ r3;  // (m_loc&7)==r3 since seg*8 ≡ 0 mod 8
#pragma unroll
    for (int i = 0; i < 4; ++i) {
      const int seg = w * 4 + i;
      const int mloc = seg * 8 + r3;
      aG[i] = (const char*)values + (size_t)(m0 + mloc) * (ND * 4) + ca * 16;
      aL[i] = seg * 1024;
    }
  }
  const char* bG[2];
  uint32_t bL[2];
  {
    const int cb = (lane & 3) ^ ((lane >> 3) & 3);
#pragma unroll
    for (int i = 0; i < 2; ++i) {
      const int seg = w * 2 + i;
      const int nloc = seg * 16 + (lane >> 2);
      bG[i] = (const char*)W1T + (size_t)(n0 + nloc) * (ND * 2) + cb * 16;
      bL[i] = 16384 + seg * 1024;
    }
  }

  // fragment read offsets (A frag: lane holds A[m=l15][k=quad*8+j], fp32 chunks 2q,2q+1)
  uint32_t aOff[4][2], bOff[4];
  {
    const int p0 = (2 * quad) ^ (l15 & 7);
#pragma unroll
    for (int ri = 0; ri < 4; ++ri) {
      const int m = wr * 64 + ri * 16 + l15;
      aOff[ri][0] = m * 128 + p0 * 16;
      aOff[ri][1] = m * 128 + (p0 ^ 1) * 16;
    }
    const int pb = quad ^ ((l15 >> 1) & 3);
#pragma unroll
    for (int ci = 0; ci < 4; ++ci) {
      const int n = wc * 64 + ci * 16 + l15;
      bOff[ci] = 16384 + n * 64 + pb * 16;
    }
  }

  f32x4 acc[4][4];
#pragma unroll
  for (int i = 0; i < 4; ++i)
#pragma unroll
    for (int j = 0; j < 4; ++j) acc[i][j] = (f32x4){0.f, 0.f, 0.f, 0.f};

  for (int kt = 0; kt < 32; ++kt) {
    __syncthreads();  // previous frag reads done before DMA overwrites
    const size_t aCol = (size_t)kt * 128;
    const size_t bCol = (size_t)kt * 64;
#pragma unroll
    for (int i = 0; i < 4; ++i) glds16(aG[i] + aCol, lds + aL[i]);
#pragma unroll
    for (int i = 0; i < 2; ++i) glds16(bG[i] + bCol, lds + bL[i]);
    __syncthreads();  // drains vmcnt: staging visible

    bf16x8 af[4];
#pragma unroll
    for (int ri = 0; ri < 4; ++ri) {
      f32x4 v0 = *(const f32x4*)(lds + aOff[ri][0]);  // k j=0..3
      f32x4 v1 = *(const f32x4*)(lds + aOff[ri][1]);  // k j=4..7
      union { uint32_t u[4]; bf16x8 v; } cvt;
      cvt.u[0] = pack_bf16_trunc(v0.x, v0.y);
      cvt.u[1] = pack_bf16_trunc(v0.z, v0.w);
      cvt.u[2] = pack_bf16_trunc(v1.x, v1.y);
      cvt.u[3] = pack_bf16_trunc(v1.z, v1.w);
      af[ri] = cvt.v;
    }
    bf16x8 bfg[4];
#pragma unroll
    for (int ci = 0; ci < 4; ++ci) {
      union { f32x4 f; bf16x8 v; } u;
      u.f = *(const f32x4*)(lds + bOff[ci]);
      bfg[ci] = u.v;
    }
#pragma unroll
    for (int ri = 0; ri < 4; ++ri)
#pragma unroll
      for (int ci = 0; ci < 4; ++ci)
        acc[ri][ci] =
            __builtin_amdgcn_mfma_f32_16x16x32_bf16(af[ri], bfg[ci], acc[ri][ci], 0, 0, 0);
  }

  // epilogue: score_partial[row] = sum_col tanh(acc + pq[b][col]) * V[col]
  // C/D layout: col = lane&15, row = quad*4 + reg   (m89/m91-verified)
  const int b = m0 >> 11;  // 2048 rows per batch, tiles never straddle
  float vv[4], qq[4];
#pragma unroll
  for (int ci = 0; ci < 4; ++ci) {
    const int col = n0 + wc * 64 + ci * 16 + l15;
    vv[ci] = V[col];
    qq[ci] = pq[b * NU + col];
  }
#pragma unroll
  for (int ri = 0; ri < 4; ++ri) {
    float p0 = 0.f, p1 = 0.f, p2 = 0.f, p3 = 0.f;
#pragma unroll
    for (int ci = 0; ci < 4; ++ci) {
      f32x4 a = acc[ri][ci];
      p0 += fast_tanh(a.x + qq[ci]) * vv[ci];
      p1 += fast_tanh(a.y + qq[ci]) * vv[ci];
      p2 += fast_tanh(a.z + qq[ci]) * vv[ci];
      p3 += fast_tanh(a.w + qq[ci]) * vv[ci];
    }
#pragma unroll
    for (int mask = 1; mask < 16; mask <<= 1) {  // reduce over the 16 col-lanes
      p0 += __shfl_xor(p0, mask);
      p1 += __shfl_xor(p1, mask);
      p2 += __shfl_xor(p2, mask);
      p3 += __shfl_xor(p3, mask);
    }
    if (l15 == 0) {
      const int rbase = m0 + wr * 64 + ri * 16 + quad * 4;
      atomicAdd(&score[rbase + 0], p0);
      atomicAdd(&score[rbase + 1], p1);
      atomicAdd(&score[rbase + 2], p2);
      atomicAdd(&score[rbase + 3], p3);
    }
  }
}

// ---------------- softmax over S per batch; writes attention output -------------
__global__ __launch_bounds__(256) void k_softmax(const float* __restrict__ score,
                                                 float* __restrict__ attn) {
  __shared__ float red[8];
  const int b = blockIdx.x, tid = threadIdx.x;
  const int w = tid >> 6, lane = tid & 63;
  const float* s = score + b * NS;
  float v[8];
  float mx = -3.4e38f;
#pragma unroll
  for (int j = 0; j < 8; ++j) {
    v[j] = s[tid + j * 256];
    mx = fmaxf(mx, v[j]);
  }
#pragma unroll
  for (int mask = 1; mask < 64; mask <<= 1) mx = fmaxf(mx, __shfl_xor(mx, mask));
  if (lane == 0) red[w] = mx;
  __syncthreads();
  mx = fmaxf(fmaxf(red[0], red[1]), fmaxf(red[2], red[3]));
  float sum = 0.f;
#pragma unroll
  for (int j = 0; j < 8; ++j) {
    v[j] = __expf(v[j] - mx);
    sum += v[j];
  }
#pragma unroll
  for (int mask = 1; mask < 64; mask <<= 1) sum += __shfl_xor(sum, mask);
  if (lane == 0) red[4 + w] = sum;
  __syncthreads();
  const float inv = 1.0f / (red[4] + red[5] + red[6] + red[7]);
  float* o = attn + b * NS;
#pragma unroll
  for (int j = 0; j < 8; ++j) o[tid + j * 256] = v[j] * inv;
}

// ---------------- context = sum_s attn * values : partials then reduce ----------
__global__ __launch_bounds__(256) void k_ctx_part(const float* __restrict__ values,
                                                  const float* __restrict__ attn,
                                                  float* __restrict__ part) {
  const int sc = blockIdx.x, b = blockIdx.y, tid = threadIdx.x;
  const int s0 = sc * 64;
  const f32x4* vb = (const f32x4*)(values + (size_t)(b * NS + s0) * ND);
  const float* ab = attn + b * NS + s0;
  f32x4 acc = (f32x4){0.f, 0.f, 0.f, 0.f};
#pragma unroll 4
  for (int s = 0; s < 64; ++s) acc += ab[s] * vb[(size_t)s * 256 + tid];
  *(f32x4*)(part + (size_t)(b * 32 + sc) * ND + tid * 4) = acc;
}

__global__ __launch_bounds__(256) void k_ctx_red(const float* __restrict__ part,
                                                 float* __restrict__ ctx) {
  const int b = blockIdx.x, tid = threadIdx.x;
  f32x4 acc = (f32x4){0.f, 0.f, 0.f, 0.f};
#pragma unroll
  for (int sc = 0; sc < 32; ++sc)
    acc += *(const f32x4*)(part + (size_t)(b * 32 + sc) * ND + tid * 4);
  *(f32x4*)(ctx + (size_t)b * ND + tid * 4) = acc;
}

extern "C" void kernel_launch(void* const* d_in, const int* in_sizes, int n_in,
                              void* d_out, int out_size, void* d_ws, size_t ws_size,
                              hipStream_t stream) {
  const float* query  = (const float*)d_in[0];
  const float* values = (const float*)d_in[1];
  const float* W1     = (const float*)d_in[2];
  const float* b1     = (const float*)d_in[3];
  const float* W2     = (const float*)d_in[4];
  const float* b2     = (const float*)d_in[5];
  const float* V      = (const float*)d_in[6];
  // d_in[7] = bV: uniform shift of scores -> cancels in softmax; not an output.

  char* ws = (char*)d_ws;
  unsigned short* W1T = (unsigned short*)ws;                 // 2 MiB  bf16 W1^T
  float* pq    = (float*)(ws + (2u << 20));                  // 128 KiB
  float* score = (float*)(ws + (2u << 20) + (128u << 10));   // 256 KiB
  float* part  = (float*)(ws + (2u << 20) + (384u << 10));   // 4 MiB
  // total ws use: ~6.4 MiB

  float* ctx  = (float*)d_out;            // context [32,1024]
  float* attn = (float*)d_out + NB * ND;  // attention [32,2048,1]

  hipMemsetAsync(score, 0, NM * sizeof(float), stream);
  k_w1t<<<dim3(16, 16), 256, 0, stream>>>(W1, W1T);
  k_pq<<<dim3(4, NB), 256, 0, stream>>>(query, W2, b1, b2, pq);
  k_score<<<dim3(8, 512), 256, 0, stream>>>(values, W1T, pq, V, score);
  k_softmax<<<NB, 256, 0, stream>>>(score, attn);
  k_ctx_part<<<dim3(32, NB), 256, 0, stream>>>(values, attn, part);
  k_ctx_red<<<NB, 256, 0, stream>>>(part, ctx);
}

// Round 2
// 678.548 us; speedup vs baseline: 1.0434x; 1.0434x over previous
//
#include <hip/hip_runtime.h>
#include <stdint.h>

typedef float f32x4 __attribute__((ext_vector_type(4)));
typedef short bf16x8 __attribute__((ext_vector_type(8)));

#define AS1 __attribute__((address_space(1)))
#define AS3 __attribute__((address_space(3)))

#define NB 32
#define NS 2048
#define ND 1024
#define NU 1024
#define NM (NB * NS)  // 65536 rows

// async 16B global->LDS (gfx950). LDS dest = wave-uniform base + lane*16.
__device__ __forceinline__ void glds16(const void* g, void* l) {
  __builtin_amdgcn_global_load_lds((const AS1 uint32_t*)g, (AS3 uint32_t*)l, 16, 0, 0);
}

__device__ __forceinline__ unsigned short bf16_rne(float f) {
  uint32_t u = __float_as_uint(f);
  u += 0x7fffu + ((u >> 16) & 1u);
  return (unsigned short)(u >> 16);
}

// (bf16_trunc(hi) << 16) | bf16_trunc(lo) in one v_perm_b32
__device__ __forceinline__ uint32_t pack_bf16_trunc(float lo, float hi) {
  return __builtin_amdgcn_perm(__float_as_uint(hi), __float_as_uint(lo), 0x07060302u);
}

__device__ __forceinline__ float fast_tanh(float x) {
  float e = __expf(2.0f * x);          // x->+inf: e=inf -> 1 ; x->-inf: e=0 -> -1
  return 1.0f - 2.0f / (e + 1.0f);
}

// ---------------- W1[k][u] fp32 -> W1T[u][k] bf16 (RNE) -------------------------
__global__ __launch_bounds__(256) void k_w1t(const float* __restrict__ W1,
                                             unsigned short* __restrict__ W1T) {
  __shared__ float t[64][65];  // +1 pad: conflict-free column reads
  const int n0 = blockIdx.x * 64, k0 = blockIdx.y * 64;
  const int tid = threadIdx.x;
  {
    const int r = tid >> 4, c4 = (tid & 15) << 2;
#pragma unroll
    for (int i = 0; i < 4; ++i) {
      f32x4 v = *(const f32x4*)(W1 + (size_t)(k0 + r + i * 16) * NU + n0 + c4);
      t[r + i * 16][c4 + 0] = v.x;
      t[r + i * 16][c4 + 1] = v.y;
      t[r + i * 16][c4 + 2] = v.z;
      t[r + i * 16][c4 + 3] = v.w;
    }
  }
  __syncthreads();
  const int rr = tid >> 2, cc = tid & 3;  // rr: local u-row, cc: 16-k chunk
  uint32_t o[8];
#pragma unroll
  for (int p = 0; p < 8; ++p) {
    float f0 = t[cc * 16 + 2 * p + 0][rr];
    float f1 = t[cc * 16 + 2 * p + 1][rr];
    o[p] = (uint32_t)bf16_rne(f0) | ((uint32_t)bf16_rne(f1) << 16);
  }
  unsigned short* dst = W1T + (size_t)(n0 + rr) * ND + k0 + cc * 16;
  *(uint4*)(dst + 0) = make_uint4(o[0], o[1], o[2], o[3]);
  *(uint4*)(dst + 8) = make_uint4(o[4], o[5], o[6], o[7]);
}

// ---------------- pq[b][u] = query[b]·W2[:,u] + b1[u] + b2[u] -------------------
__global__ __launch_bounds__(256) void k_pq(const float* __restrict__ query,
                                            const float* __restrict__ W2,
                                            const float* __restrict__ b1,
                                            const float* __restrict__ b2,
                                            float* __restrict__ pq) {
  const int u = blockIdx.x * 256 + threadIdx.x;
  const int b = blockIdx.y;
  const float* q = query + b * ND;  // uniform -> scalar loads
  float a0 = b1[u] + b2[u], a1 = 0.f, a2 = 0.f, a3 = 0.f;
  for (int k = 0; k < ND; k += 16) {
#pragma unroll
    for (int j = 0; j < 16; j += 4) {
      a0 = fmaf(q[k + j + 0], W2[(size_t)(k + j + 0) * NU + u], a0);
      a1 = fmaf(q[k + j + 1], W2[(size_t)(k + j + 1) * NU + u], a1);
      a2 = fmaf(q[k + j + 2], W2[(size_t)(k + j + 2) * NU + u], a2);
      a3 = fmaf(q[k + j + 3], W2[(size_t)(k + j + 3) * NU + u], a3);
    }
  }
  pq[b * NU + u] = (a0 + a1) + (a2 + a3);
}

// ---------------- fused GEMM (values@W1) + tanh·V score reduction ---------------
// grid: flat 4096 blocks. XCD swizzle: bid&7 = XCD (round-robin dispatch); each
// XCD owns 64 contiguous m-tiles x all 8 n-chunks, so the 8 blocks sharing an
// A-tile co-reside on one XCD -> A re-reads hit that XCD's L2; B (2 MiB bf16)
// stays L2-resident. 256 threads (4 waves 2x2), 128x128 tile, BK=32.
// A tile: fp32 in LDS [128 rows][8 x 16B chunks], chunk c stored at pos c^(m&7).
// B tile: bf16 in LDS [128 n-rows][4 x 16B chunks], chunk c at pos c^((n>>1)&3).
__global__ __launch_bounds__(256) void k_score(const float* __restrict__ values,
                                               const unsigned short* __restrict__ W1T,
                                               const float* __restrict__ pq,
                                               const float* __restrict__ V,
                                               float* __restrict__ score) {
  __shared__ f32x4 lds4[1536];  // 24 KiB: [0,16K)=A, [16K,24K)=B
  char* lds = (char*)lds4;

  const int tid = threadIdx.x;
  const int lane = tid & 63;
  const int w = tid >> 6;
  const int wr = w >> 1, wc = w & 1;      // wave 2x2, each 64x64
  const int quad = lane >> 4, l15 = lane & 15;

  const int bid = blockIdx.x;
  const int xcd = bid & 7;
  const int local = bid >> 3;
  const int mt = xcd * 64 + (local >> 3);
  const int nc = local & 7;
  const int m0 = mt * 128, n0 = nc * 128;

  // staging: A = 4 glds/wave (16KB tile), B = 2 glds/wave (8KB tile)
  const char* aG[4];
  uint32_t aL[4];
  {
    const int p = lane & 7, r3 = lane >> 3;
    const int ca = p ^ r3;  // (m_loc&7)==r3 since seg*8 ≡ 0 mod 8
#pragma unroll
    for (int i = 0; i < 4; ++i) {
      const int seg = w * 4 + i;
      const int mloc = seg * 8 + r3;
      aG[i] = (const char*)values + (size_t)(m0 + mloc) * (ND * 4) + ca * 16;
      aL[i] = seg * 1024;
    }
  }
  const char* bG[2];
  uint32_t bL[2];
  {
    const int cb = (lane & 3) ^ ((lane >> 3) & 3);
#pragma unroll
    for (int i = 0; i < 2; ++i) {
      const int seg = w * 2 + i;
      const int nloc = seg * 16 + (lane >> 2);
      bG[i] = (const char*)W1T + (size_t)(n0 + nloc) * (ND * 2) + cb * 16;
      bL[i] = 16384 + seg * 1024;
    }
  }

  // fragment read offsets (A frag: lane holds A[m=l15][k=quad*8+j], fp32 chunks 2q,2q+1)
  uint32_t aOff[4][2], bOff[4];
  {
    const int p0 = (2 * quad) ^ (l15 & 7);
#pragma unroll
    for (int ri = 0; ri < 4; ++ri) {
      const int m = wr * 64 + ri * 16 + l15;
      aOff[ri][0] = m * 128 + p0 * 16;
      aOff[ri][1] = m * 128 + (p0 ^ 1) * 16;
    }
    const int pb = quad ^ ((l15 >> 1) & 3);
#pragma unroll
    for (int ci = 0; ci < 4; ++ci) {
      const int n = wc * 64 + ci * 16 + l15;
      bOff[ci] = 16384 + n * 64 + pb * 16;
    }
  }

  f32x4 acc[4][4];
#pragma unroll
  for (int i = 0; i < 4; ++i)
#pragma unroll
    for (int j = 0; j < 4; ++j) acc[i][j] = (f32x4){0.f, 0.f, 0.f, 0.f};

  for (int kt = 0; kt < 32; ++kt) {
    __syncthreads();  // previous frag reads done before DMA overwrites
    const size_t aCol = (size_t)kt * 128;
    const size_t bCol = (size_t)kt * 64;
#pragma unroll
    for (int i = 0; i < 4; ++i) glds16(aG[i] + aCol, lds + aL[i]);
#pragma unroll
    for (int i = 0; i < 2; ++i) glds16(bG[i] + bCol, lds + bL[i]);
    __syncthreads();  // drains vmcnt: staging visible

    bf16x8 af[4];
#pragma unroll
    for (int ri = 0; ri < 4; ++ri) {
      f32x4 v0 = *(const f32x4*)(lds + aOff[ri][0]);  // k j=0..3
      f32x4 v1 = *(const f32x4*)(lds + aOff[ri][1]);  // k j=4..7
      union { uint32_t u[4]; bf16x8 v; } cvt;
      cvt.u[0] = pack_bf16_trunc(v0.x, v0.y);
      cvt.u[1] = pack_bf16_trunc(v0.z, v0.w);
      cvt.u[2] = pack_bf16_trunc(v1.x, v1.y);
      cvt.u[3] = pack_bf16_trunc(v1.z, v1.w);
      af[ri] = cvt.v;
    }
    bf16x8 bfg[4];
#pragma unroll
    for (int ci = 0; ci < 4; ++ci) {
      union { f32x4 f; bf16x8 v; } u;
      u.f = *(const f32x4*)(lds + bOff[ci]);
      bfg[ci] = u.v;
    }
#pragma unroll
    for (int ri = 0; ri < 4; ++ri)
#pragma unroll
      for (int ci = 0; ci < 4; ++ci)
        acc[ri][ci] =
            __builtin_amdgcn_mfma_f32_16x16x32_bf16(af[ri], bfg[ci], acc[ri][ci], 0, 0, 0);
  }

  // epilogue: score_partial[row] = sum_col tanh(acc + pq[b][col]) * V[col]
  // C/D layout: col = lane&15, row = quad*4 + reg   (m89/m91-verified)
  const int b = m0 >> 11;  // 2048 rows per batch, tiles never straddle
  float vv[4], qq[4];
#pragma unroll
  for (int ci = 0; ci < 4; ++ci) {
    const int col = n0 + wc * 64 + ci * 16 + l15;
    vv[ci] = V[col];
    qq[ci] = pq[b * NU + col];
  }
#pragma unroll
  for (int ri = 0; ri < 4; ++ri) {
    float p0 = 0.f, p1 = 0.f, p2 = 0.f, p3 = 0.f;
#pragma unroll
    for (int ci = 0; ci < 4; ++ci) {
      f32x4 a = acc[ri][ci];
      p0 += fast_tanh(a.x + qq[ci]) * vv[ci];
      p1 += fast_tanh(a.y + qq[ci]) * vv[ci];
      p2 += fast_tanh(a.z + qq[ci]) * vv[ci];
      p3 += fast_tanh(a.w + qq[ci]) * vv[ci];
    }
#pragma unroll
    for (int mask = 1; mask < 16; mask <<= 1) {  // reduce over the 16 col-lanes
      p0 += __shfl_xor(p0, mask);
      p1 += __shfl_xor(p1, mask);
      p2 += __shfl_xor(p2, mask);
      p3 += __shfl_xor(p3, mask);
    }
    if (l15 == 0) {
      const int rbase = m0 + wr * 64 + ri * 16 + quad * 4;
      atomicAdd(&score[rbase + 0], p0);
      atomicAdd(&score[rbase + 1], p1);
      atomicAdd(&score[rbase + 2], p2);
      atomicAdd(&score[rbase + 3], p3);
    }
  }
}

// ---------------- softmax over S per batch; writes attention output -------------
__global__ __launch_bounds__(256) void k_softmax(const float* __restrict__ score,
                                                 float* __restrict__ attn) {
  __shared__ float red[8];
  const int b = blockIdx.x, tid = threadIdx.x;
  const int w = tid >> 6, lane = tid & 63;
  const float* s = score + b * NS;
  float v[8];
  float mx = -3.4e38f;
#pragma unroll
  for (int j = 0; j < 8; ++j) {
    v[j] = s[tid + j * 256];
    mx = fmaxf(mx, v[j]);
  }
#pragma unroll
  for (int mask = 1; mask < 64; mask <<= 1) mx = fmaxf(mx, __shfl_xor(mx, mask));
  if (lane == 0) red[w] = mx;
  __syncthreads();
  mx = fmaxf(fmaxf(red[0], red[1]), fmaxf(red[2], red[3]));
  float sum = 0.f;
#pragma unroll
  for (int j = 0; j < 8; ++j) {
    v[j] = __expf(v[j] - mx);
    sum += v[j];
  }
#pragma unroll
  for (int mask = 1; mask < 64; mask <<= 1) sum += __shfl_xor(sum, mask);
  if (lane == 0) red[4 + w] = sum;
  __syncthreads();
  const float inv = 1.0f / (red[4] + red[5] + red[6] + red[7]);
  float* o = attn + b * NS;
#pragma unroll
  for (int j = 0; j < 8; ++j) o[tid + j * 256] = v[j] * inv;
}

// ---------------- context = sum_s attn * values : partials then reduce ----------
// 8 independent f32x4 loads in flight per thread (128 B) -> Little's-law depth
// for HBM latency; attn loads are wave-uniform -> s_load.
__global__ __launch_bounds__(256) void k_ctx_part(const float* __restrict__ values,
                                                  const float* __restrict__ attn,
                                                  float* __restrict__ part) {
  const int sc = blockIdx.x, b = blockIdx.y, tid = threadIdx.x;
  const int s0 = sc * 64;
  const f32x4* vb = (const f32x4*)(values + (size_t)(b * NS + s0) * ND);
  const float* ab = attn + b * NS + s0;
  f32x4 acc0 = (f32x4){0.f, 0.f, 0.f, 0.f};
  f32x4 acc1 = (f32x4){0.f, 0.f, 0.f, 0.f};
  for (int s = 0; s < 64; s += 8) {
    f32x4 v0 = vb[(size_t)(s + 0) * 256 + tid];
    f32x4 v1 = vb[(size_t)(s + 1) * 256 + tid];
    f32x4 v2 = vb[(size_t)(s + 2) * 256 + tid];
    f32x4 v3 = vb[(size_t)(s + 3) * 256 + tid];
    f32x4 v4 = vb[(size_t)(s + 4) * 256 + tid];
    f32x4 v5 = vb[(size_t)(s + 5) * 256 + tid];
    f32x4 v6 = vb[(size_t)(s + 6) * 256 + tid];
    f32x4 v7 = vb[(size_t)(s + 7) * 256 + tid];
    acc0 += ab[s + 0] * v0;
    acc1 += ab[s + 1] * v1;
    acc0 += ab[s + 2] * v2;
    acc1 += ab[s + 3] * v3;
    acc0 += ab[s + 4] * v4;
    acc1 += ab[s + 5] * v5;
    acc0 += ab[s + 6] * v6;
    acc1 += ab[s + 7] * v7;
  }
  *(f32x4*)(part + (size_t)(b * 32 + sc) * ND + tid * 4) = acc0 + acc1;
}

__global__ __launch_bounds__(256) void k_ctx_red(const float* __restrict__ part,
                                                 float* __restrict__ ctx) {
  const int b = blockIdx.x, tid = threadIdx.x;
  f32x4 acc = (f32x4){0.f, 0.f, 0.f, 0.f};
#pragma unroll
  for (int sc = 0; sc < 32; ++sc)
    acc += *(const f32x4*)(part + (size_t)(b * 32 + sc) * ND + tid * 4);
  *(f32x4*)(ctx + (size_t)b * ND + tid * 4) = acc;
}

extern "C" void kernel_launch(void* const* d_in, const int* in_sizes, int n_in,
                              void* d_out, int out_size, void* d_ws, size_t ws_size,
                              hipStream_t stream) {
  const float* query  = (const float*)d_in[0];
  const float* values = (const float*)d_in[1];
  const float* W1     = (const float*)d_in[2];
  const float* b1     = (const float*)d_in[3];
  const float* W2     = (const float*)d_in[4];
  const float* b2     = (const float*)d_in[5];
  const float* V      = (const float*)d_in[6];
  // d_in[7] = bV: uniform shift of scores -> cancels in softmax; not an output.

  char* ws = (char*)d_ws;
  unsigned short* W1T = (unsigned short*)ws;                 // 2 MiB  bf16 W1^T
  float* pq    = (float*)(ws + (2u << 20));                  // 128 KiB
  float* score = (float*)(ws + (2u << 20) + (128u << 10));   // 256 KiB
  float* part  = (float*)(ws + (2u << 20) + (384u << 10));   // 4 MiB
  // total ws use: ~6.4 MiB

  float* ctx  = (float*)d_out;            // context [32,1024]
  float* attn = (float*)d_out + NB * ND;  // attention [32,2048,1]

  hipMemsetAsync(score, 0, NM * sizeof(float), stream);
  k_w1t<<<dim3(16, 16), 256, 0, stream>>>(W1, W1T);
  k_pq<<<dim3(4, NB), 256, 0, stream>>>(query, W2, b1, b2, pq);
  k_score<<<dim3(4096), 256, 0, stream>>>(values, W1T, pq, V, score);
  k_softmax<<<NB, 256, 0, stream>>>(score, attn);
  k_ctx_part<<<dim3(32, NB), 256, 0, stream>>>(values, attn, part);
  k_ctx_red<<<NB, 256, 0, stream>>>(part, ctx);
}

// Round 3
// 665.473 us; speedup vs baseline: 1.0639x; 1.0196x over previous
//
#include <hip/hip_runtime.h>
#include <stdint.h>

typedef float f32x4 __attribute__((ext_vector_type(4)));
typedef short bf16x8 __attribute__((ext_vector_type(8)));
typedef _Float16 f16x8 __attribute__((ext_vector_type(8)));

#define AS1 __attribute__((address_space(1)))
#define AS3 __attribute__((address_space(3)))

#define NB 32
#define NS 2048
#define ND 1024
#define NU 1024
#define NM (NB * NS)  // 65536 rows

// async 16B global->LDS (gfx950). LDS dest = wave-uniform base + lane*16.
__device__ __forceinline__ void glds16(const void* g, void* l) {
  __builtin_amdgcn_global_load_lds((const AS1 uint32_t*)g, (AS3 uint32_t*)l, 16, 0, 0);
}

__device__ __forceinline__ unsigned short bf16_rne(float f) {
  uint32_t u = __float_as_uint(f);
  u += 0x7fffu + ((u >> 16) & 1u);
  return (unsigned short)(u >> 16);
}

// two fp32 -> packed fp16 pair (RNE via v_cvt_f16_f32)
__device__ __forceinline__ uint32_t h2pack(float lo, float hi) {
  union { _Float16 h[2]; uint32_t u; } p;
  p.h[0] = (_Float16)lo;
  p.h[1] = (_Float16)hi;
  return p.u;
}

// (bf16_trunc(hi) << 16) | bf16_trunc(lo) in one v_perm_b32
__device__ __forceinline__ uint32_t pack_bf16_trunc(float lo, float hi) {
  return __builtin_amdgcn_perm(__float_as_uint(hi), __float_as_uint(lo), 0x07060302u);
}

__device__ __forceinline__ float fast_tanh(float x) {
  float e = __expf(2.0f * x);
  return 1.0f - 2.0f / (e + 1.0f);
}

// ---------------- values fp32 -> fp16 (RNE), 67.1M elems ------------------------
__global__ __launch_bounds__(256) void k_cvt(const float* __restrict__ values,
                                             _Float16* __restrict__ values_h) {
  const size_t gid = (size_t)blockIdx.x * 256 + threadIdx.x;
#pragma unroll 2
  for (int it = 0; it < 8; ++it) {
    const size_t e0 = gid * 8 + (size_t)it * 8388608;  // 1,048,576 thr * 8 elems
    f32x4 v0 = *(const f32x4*)(values + e0);
    f32x4 v1 = *(const f32x4*)(values + e0 + 4);
    uint4 o;
    o.x = h2pack(v0.x, v0.y);
    o.y = h2pack(v0.z, v0.w);
    o.z = h2pack(v1.x, v1.y);
    o.w = h2pack(v1.z, v1.w);
    *(uint4*)(values_h + e0) = o;
  }
}

// ---------------- W1[k][u] fp32 -> W1T[u][k] fp16 (RNE) -------------------------
__global__ __launch_bounds__(256) void k_w1t_h(const float* __restrict__ W1,
                                               _Float16* __restrict__ W1T) {
  __shared__ float t[64][65];
  const int n0 = blockIdx.x * 64, k0 = blockIdx.y * 64;
  const int tid = threadIdx.x;
  {
    const int r = tid >> 4, c4 = (tid & 15) << 2;
#pragma unroll
    for (int i = 0; i < 4; ++i) {
      f32x4 v = *(const f32x4*)(W1 + (size_t)(k0 + r + i * 16) * NU + n0 + c4);
      t[r + i * 16][c4 + 0] = v.x;
      t[r + i * 16][c4 + 1] = v.y;
      t[r + i * 16][c4 + 2] = v.z;
      t[r + i * 16][c4 + 3] = v.w;
    }
  }
  __syncthreads();
  const int rr = tid >> 2, cc = tid & 3;
  uint32_t o[8];
#pragma unroll
  for (int p = 0; p < 8; ++p)
    o[p] = h2pack(t[cc * 16 + 2 * p + 0][rr], t[cc * 16 + 2 * p + 1][rr]);
  _Float16* dst = W1T + (size_t)(n0 + rr) * ND + k0 + cc * 16;
  *(uint4*)(dst + 0) = make_uint4(o[0], o[1], o[2], o[3]);
  *(uint4*)(dst + 8) = make_uint4(o[4], o[5], o[6], o[7]);
}

// ---------------- W1 -> bf16 W1T (fallback path) --------------------------------
__global__ __launch_bounds__(256) void k_w1t(const float* __restrict__ W1,
                                             unsigned short* __restrict__ W1T) {
  __shared__ float t[64][65];
  const int n0 = blockIdx.x * 64, k0 = blockIdx.y * 64;
  const int tid = threadIdx.x;
  {
    const int r = tid >> 4, c4 = (tid & 15) << 2;
#pragma unroll
    for (int i = 0; i < 4; ++i) {
      f32x4 v = *(const f32x4*)(W1 + (size_t)(k0 + r + i * 16) * NU + n0 + c4);
      t[r + i * 16][c4 + 0] = v.x;
      t[r + i * 16][c4 + 1] = v.y;
      t[r + i * 16][c4 + 2] = v.z;
      t[r + i * 16][c4 + 3] = v.w;
    }
  }
  __syncthreads();
  const int rr = tid >> 2, cc = tid & 3;
  uint32_t o[8];
#pragma unroll
  for (int p = 0; p < 8; ++p) {
    float f0 = t[cc * 16 + 2 * p + 0][rr];
    float f1 = t[cc * 16 + 2 * p + 1][rr];
    o[p] = (uint32_t)bf16_rne(f0) | ((uint32_t)bf16_rne(f1) << 16);
  }
  unsigned short* dst = W1T + (size_t)(n0 + rr) * ND + k0 + cc * 16;
  *(uint4*)(dst + 0) = make_uint4(o[0], o[1], o[2], o[3]);
  *(uint4*)(dst + 8) = make_uint4(o[4], o[5], o[6], o[7]);
}

// ---------------- pq partials over k-chunks (f32x4 ILP) -------------------------
__global__ __launch_bounds__(256) void k_pq(const float* __restrict__ query,
                                            const float* __restrict__ W2,
                                            float* __restrict__ pq_part) {
  const int kc = blockIdx.x, b = blockIdx.y;
  const int u4 = threadIdx.x * 4;
  const float* q = query + b * ND + kc * 256;  // wave-uniform -> s_load
  f32x4 a0 = (f32x4){0.f, 0.f, 0.f, 0.f}, a1 = a0;
  const float* w = W2 + (size_t)kc * 256 * NU + u4;
  for (int k = 0; k < 256; k += 8) {
#pragma unroll
    for (int j = 0; j < 8; j += 2) {
      a0 += q[k + j + 0] * *(const f32x4*)(w + (size_t)(k + j + 0) * NU);
      a1 += q[k + j + 1] * *(const f32x4*)(w + (size_t)(k + j + 1) * NU);
    }
  }
  *(f32x4*)(pq_part + (size_t)(kc * NB + b) * NU + u4) = a0 + a1;
}

__global__ __launch_bounds__(256) void k_pq_red(const float* __restrict__ pq_part,
                                                const float* __restrict__ b1,
                                                const float* __restrict__ b2,
                                                float* __restrict__ pq) {
  const int b = blockIdx.x, u4 = threadIdx.x * 4;
  f32x4 acc = *(const f32x4*)(b1 + u4) + *(const f32x4*)(b2 + u4);
#pragma unroll
  for (int kc = 0; kc < 4; ++kc)
    acc += *(const f32x4*)(pq_part + (size_t)(kc * NB + b) * NU + u4);
  *(f32x4*)(pq + (size_t)b * NU + u4) = acc;
}

// ---------------- fused GEMM (values_h @ W1T_h) + tanh·V score (fp16 A+B) -------
// grid flat 4096; XCD swizzle: bid&7=XCD owns 64 contiguous m-tiles x 8 n-chunks.
// LDS 16KB: A [128 rows][4 x 16B fp16 chunks] chunk c at pos c^(m&3); B same at 8K.
__global__ __launch_bounds__(256) void k_score_h(const _Float16* __restrict__ valh,
                                                 const _Float16* __restrict__ W1T,
                                                 const float* __restrict__ pq,
                                                 const float* __restrict__ V,
                                                 float* __restrict__ score) {
  __shared__ f32x4 lds4[1024];  // 16 KiB: [0,8K)=A, [8K,16K)=B
  char* lds = (char*)lds4;

  const int tid = threadIdx.x;
  const int lane = tid & 63;
  const int w = tid >> 6;
  const int wr = w >> 1, wc = w & 1;
  const int quad = lane >> 4, l15 = lane & 15;

  const int bid = blockIdx.x;
  const int xcd = bid & 7;
  const int local = bid >> 3;
  const int mt = xcd * 64 + (local >> 3);
  const int nc = local & 7;
  const int m0 = mt * 128, n0 = nc * 128;

  // staging: A = 2 glds/wave (8KB tile), B = 2 glds/wave (8KB tile)
  const char* aG[2];
  const char* bG[2];
  uint32_t aL[2], bL[2];
  {
    const int r = lane >> 2;                       // 16 rows per glds
    const int ca = (lane & 3) ^ (r & 3);           // swizzled chunk fetch
#pragma unroll
    for (int i = 0; i < 2; ++i) {
      const int seg = w * 2 + i;
      const int rloc = seg * 16 + r;
      aG[i] = (const char*)valh + (size_t)(m0 + rloc) * (ND * 2) + ca * 16;
      aL[i] = seg * 1024;
      bG[i] = (const char*)W1T + (size_t)(n0 + rloc) * (ND * 2) + ca * 16;
      bL[i] = 8192 + seg * 1024;
    }
  }

  // fragment offsets: lane holds X[r=l15][k=quad*8+j] -> chunk quad at pos quad^(r&3)
  uint32_t aOff[4], bOff[4];
  {
    const int pp = (quad ^ (l15 & 3)) * 16;
#pragma unroll
    for (int ri = 0; ri < 4; ++ri) aOff[ri] = (wr * 64 + ri * 16 + l15) * 64 + pp;
#pragma unroll
    for (int ci = 0; ci < 4; ++ci) bOff[ci] = 8192 + (wc * 64 + ci * 16 + l15) * 64 + pp;
  }

  f32x4 acc[4][4];
#pragma unroll
  for (int i = 0; i < 4; ++i)
#pragma unroll
    for (int j = 0; j < 4; ++j) acc[i][j] = (f32x4){0.f, 0.f, 0.f, 0.f};

  for (int kt = 0; kt < 32; ++kt) {
    __syncthreads();
    const size_t col = (size_t)kt * 64;  // 32 k * 2B
#pragma unroll
    for (int i = 0; i < 2; ++i) glds16(aG[i] + col, lds + aL[i]);
#pragma unroll
    for (int i = 0; i < 2; ++i) glds16(bG[i] + col, lds + bL[i]);
    __syncthreads();  // vmcnt drained: staging visible

    f16x8 af[4], bf[4];
#pragma unroll
    for (int ri = 0; ri < 4; ++ri) {
      union { f32x4 f; f16x8 h; } u;
      u.f = *(const f32x4*)(lds + aOff[ri]);
      af[ri] = u.h;
    }
#pragma unroll
    for (int ci = 0; ci < 4; ++ci) {
      union { f32x4 f; f16x8 h; } u;
      u.f = *(const f32x4*)(lds + bOff[ci]);
      bf[ci] = u.h;
    }
#pragma unroll
    for (int ri = 0; ri < 4; ++ri)
#pragma unroll
      for (int ci = 0; ci < 4; ++ci)
        acc[ri][ci] =
            __builtin_amdgcn_mfma_f32_16x16x32_f16(af[ri], bf[ci], acc[ri][ci], 0, 0, 0);
  }

  // epilogue: C/D layout col=lane&15, row=quad*4+reg (m89/m91-verified)
  const int b = m0 >> 11;
  float vv[4], qq[4];
#pragma unroll
  for (int ci = 0; ci < 4; ++ci) {
    const int col = n0 + wc * 64 + ci * 16 + l15;
    vv[ci] = V[col];
    qq[ci] = pq[b * NU + col];
  }
#pragma unroll
  for (int ri = 0; ri < 4; ++ri) {
    float p0 = 0.f, p1 = 0.f, p2 = 0.f, p3 = 0.f;
#pragma unroll
    for (int ci = 0; ci < 4; ++ci) {
      f32x4 a = acc[ri][ci];
      p0 += fast_tanh(a.x + qq[ci]) * vv[ci];
      p1 += fast_tanh(a.y + qq[ci]) * vv[ci];
      p2 += fast_tanh(a.z + qq[ci]) * vv[ci];
      p3 += fast_tanh(a.w + qq[ci]) * vv[ci];
    }
#pragma unroll
    for (int mask = 1; mask < 16; mask <<= 1) {
      p0 += __shfl_xor(p0, mask);
      p1 += __shfl_xor(p1, mask);
      p2 += __shfl_xor(p2, mask);
      p3 += __shfl_xor(p3, mask);
    }
    if (l15 == 0) {
      const int rbase = m0 + wr * 64 + ri * 16 + quad * 4;
      atomicAdd(&score[rbase + 0], p0);
      atomicAdd(&score[rbase + 1], p1);
      atomicAdd(&score[rbase + 2], p2);
      atomicAdd(&score[rbase + 3], p3);
    }
  }
}

// ---------------- fallback: fused GEMM with fp32 A staging (R2 kernel) ----------
__global__ __launch_bounds__(256) void k_score_f32(const float* __restrict__ values,
                                                   const unsigned short* __restrict__ W1T,
                                                   const float* __restrict__ pq,
                                                   const float* __restrict__ V,
                                                   float* __restrict__ score) {
  __shared__ f32x4 lds4[1536];
  char* lds = (char*)lds4;
  const int tid = threadIdx.x;
  const int lane = tid & 63;
  const int w = tid >> 6;
  const int wr = w >> 1, wc = w & 1;
  const int quad = lane >> 4, l15 = lane & 15;
  const int bid = blockIdx.x;
  const int xcd = bid & 7;
  const int local = bid >> 3;
  const int mt = xcd * 64 + (local >> 3);
  const int nc = local & 7;
  const int m0 = mt * 128, n0 = nc * 128;
  const char* aG[4];
  uint32_t aL[4];
  {
    const int p = lane & 7, r3 = lane >> 3;
    const int ca = p ^ r3;
#pragma unroll
    for (int i = 0; i < 4; ++i) {
      const int seg = w * 4 + i;
      const int mloc = seg * 8 + r3;
      aG[i] = (const char*)values + (size_t)(m0 + mloc) * (ND * 4) + ca * 16;
      aL[i] = seg * 1024;
    }
  }
  const char* bG[2];
  uint32_t bL[2];
  {
    const int cb = (lane & 3) ^ ((lane >> 3) & 3);
#pragma unroll
    for (int i = 0; i < 2; ++i) {
      const int seg = w * 2 + i;
      const int nloc = seg * 16 + (lane >> 2);
      bG[i] = (const char*)W1T + (size_t)(n0 + nloc) * (ND * 2) + cb * 16;
      bL[i] = 16384 + seg * 1024;
    }
  }
  uint32_t aOff[4][2], bOff[4];
  {
    const int p0 = (2 * quad) ^ (l15 & 7);
#pragma unroll
    for (int ri = 0; ri < 4; ++ri) {
      const int m = wr * 64 + ri * 16 + l15;
      aOff[ri][0] = m * 128 + p0 * 16;
      aOff[ri][1] = m * 128 + (p0 ^ 1) * 16;
    }
    const int pb = quad ^ ((l15 >> 1) & 3);
#pragma unroll
    for (int ci = 0; ci < 4; ++ci) {
      const int n = wc * 64 + ci * 16 + l15;
      bOff[ci] = 16384 + n * 64 + pb * 16;
    }
  }
  f32x4 acc[4][4];
#pragma unroll
  for (int i = 0; i < 4; ++i)
#pragma unroll
    for (int j = 0; j < 4; ++j) acc[i][j] = (f32x4){0.f, 0.f, 0.f, 0.f};
  for (int kt = 0; kt < 32; ++kt) {
    __syncthreads();
    const size_t aCol = (size_t)kt * 128;
    const size_t bCol = (size_t)kt * 64;
#pragma unroll
    for (int i = 0; i < 4; ++i) glds16(aG[i] + aCol, lds + aL[i]);
#pragma unroll
    for (int i = 0; i < 2; ++i) glds16(bG[i] + bCol, lds + bL[i]);
    __syncthreads();
    bf16x8 af[4];
#pragma unroll
    for (int ri = 0; ri < 4; ++ri) {
      f32x4 v0 = *(const f32x4*)(lds + aOff[ri][0]);
      f32x4 v1 = *(const f32x4*)(lds + aOff[ri][1]);
      union { uint32_t u[4]; bf16x8 v; } cvt;
      cvt.u[0] = pack_bf16_trunc(v0.x, v0.y);
      cvt.u[1] = pack_bf16_trunc(v0.z, v0.w);
      cvt.u[2] = pack_bf16_trunc(v1.x, v1.y);
      cvt.u[3] = pack_bf16_trunc(v1.z, v1.w);
      af[ri] = cvt.v;
    }
    bf16x8 bfg[4];
#pragma unroll
    for (int ci = 0; ci < 4; ++ci) {
      union { f32x4 f; bf16x8 v; } u;
      u.f = *(const f32x4*)(lds + bOff[ci]);
      bfg[ci] = u.v;
    }
#pragma unroll
    for (int ri = 0; ri < 4; ++ri)
#pragma unroll
      for (int ci = 0; ci < 4; ++ci)
        acc[ri][ci] =
            __builtin_amdgcn_mfma_f32_16x16x32_bf16(af[ri], bfg[ci], acc[ri][ci], 0, 0, 0);
  }
  const int b = m0 >> 11;
  float vv[4], qq[4];
#pragma unroll
  for (int ci = 0; ci < 4; ++ci) {
    const int col = n0 + wc * 64 + ci * 16 + l15;
    vv[ci] = V[col];
    qq[ci] = pq[b * NU + col];
  }
#pragma unroll
  for (int ri = 0; ri < 4; ++ri) {
    float p0 = 0.f, p1 = 0.f, p2 = 0.f, p3 = 0.f;
#pragma unroll
    for (int ci = 0; ci < 4; ++ci) {
      f32x4 a = acc[ri][ci];
      p0 += fast_tanh(a.x + qq[ci]) * vv[ci];
      p1 += fast_tanh(a.y + qq[ci]) * vv[ci];
      p2 += fast_tanh(a.z + qq[ci]) * vv[ci];
      p3 += fast_tanh(a.w + qq[ci]) * vv[ci];
    }
#pragma unroll
    for (int mask = 1; mask < 16; mask <<= 1) {
      p0 += __shfl_xor(p0, mask);
      p1 += __shfl_xor(p1, mask);
      p2 += __shfl_xor(p2, mask);
      p3 += __shfl_xor(p3, mask);
    }
    if (l15 == 0) {
      const int rbase = m0 + wr * 64 + ri * 16 + quad * 4;
      atomicAdd(&score[rbase + 0], p0);
      atomicAdd(&score[rbase + 1], p1);
      atomicAdd(&score[rbase + 2], p2);
      atomicAdd(&score[rbase + 3], p3);
    }
  }
}

// ---------------- softmax over S per batch; writes attention output -------------
__global__ __launch_bounds__(256) void k_softmax(const float* __restrict__ score,
                                                 float* __restrict__ attn) {
  __shared__ float red[8];
  const int b = blockIdx.x, tid = threadIdx.x;
  const int w = tid >> 6, lane = tid & 63;
  const float* s = score + b * NS;
  float v[8];
  float mx = -3.4e38f;
#pragma unroll
  for (int j = 0; j < 8; ++j) {
    v[j] = s[tid + j * 256];
    mx = fmaxf(mx, v[j]);
  }
#pragma unroll
  for (int mask = 1; mask < 64; mask <<= 1) mx = fmaxf(mx, __shfl_xor(mx, mask));
  if (lane == 0) red[w] = mx;
  __syncthreads();
  mx = fmaxf(fmaxf(red[0], red[1]), fmaxf(red[2], red[3]));
  float sum = 0.f;
#pragma unroll
  for (int j = 0; j < 8; ++j) {
    v[j] = __expf(v[j] - mx);
    sum += v[j];
  }
#pragma unroll
  for (int mask = 1; mask < 64; mask <<= 1) sum += __shfl_xor(sum, mask);
  if (lane == 0) red[4 + w] = sum;
  __syncthreads();
  const float inv = 1.0f / (red[4] + red[5] + red[6] + red[7]);
  float* o = attn + b * NS;
#pragma unroll
  for (int j = 0; j < 8; ++j) o[tid + j * 256] = v[j] * inv;
}

// ---------------- context partials from fp16 values -----------------------------
// grid (64 sc, 32 b), 128 threads. Block covers 32 s-rows; thread owns 8 d.
__global__ __launch_bounds__(128) void k_ctx_part_h(const _Float16* __restrict__ valh,
                                                    const float* __restrict__ attn,
                                                    float* __restrict__ part) {
  const int sc = blockIdx.x, b = blockIdx.y, t = threadIdx.x;
  const int row0 = b * NS + sc * 32;
  const int d8 = t * 8;
  const float* ab = attn + row0;  // wave-uniform -> s_load
  float acc[8];
#pragma unroll
  for (int i = 0; i < 8; ++i) acc[i] = 0.f;
  for (int s0 = 0; s0 < 32; s0 += 8) {
    uint4 r[8];
#pragma unroll
    for (int j = 0; j < 8; ++j)
      r[j] = *(const uint4*)(valh + (size_t)(row0 + s0 + j) * ND + d8);
#pragma unroll
    for (int j = 0; j < 8; ++j) {
      union { uint4 u; _Float16 h[8]; } c;
      c.u = r[j];
      const float a = ab[s0 + j];
#pragma unroll
      for (int i = 0; i < 8; ++i) acc[i] = fmaf(a, (float)c.h[i], acc[i]);
    }
  }
  float* o = part + (size_t)(b * 64 + sc) * ND + d8;
#pragma unroll
  for (int i = 0; i < 8; ++i) o[i] = acc[i];
}

// ---------------- fallback fp32 context partials --------------------------------
__global__ __launch_bounds__(256) void k_ctx_part_f32(const float* __restrict__ values,
                                                      const float* __restrict__ attn,
                                                      float* __restrict__ part) {
  const int sc = blockIdx.x, b = blockIdx.y, tid = threadIdx.x;
  const int s0 = sc * 64;
  const f32x4* vb = (const f32x4*)(values + (size_t)(b * NS + s0) * ND);
  const float* ab = attn + b * NS + s0;
  f32x4 acc0 = (f32x4){0.f, 0.f, 0.f, 0.f};
  f32x4 acc1 = acc0;
  for (int s = 0; s < 64; s += 8) {
    f32x4 v0 = vb[(size_t)(s + 0) * 256 + tid];
    f32x4 v1 = vb[(size_t)(s + 1) * 256 + tid];
    f32x4 v2 = vb[(size_t)(s + 2) * 256 + tid];
    f32x4 v3 = vb[(size_t)(s + 3) * 256 + tid];
    f32x4 v4 = vb[(size_t)(s + 4) * 256 + tid];
    f32x4 v5 = vb[(size_t)(s + 5) * 256 + tid];
    f32x4 v6 = vb[(size_t)(s + 6) * 256 + tid];
    f32x4 v7 = vb[(size_t)(s + 7) * 256 + tid];
    acc0 += ab[s + 0] * v0;
    acc1 += ab[s + 1] * v1;
    acc0 += ab[s + 2] * v2;
    acc1 += ab[s + 3] * v3;
    acc0 += ab[s + 4] * v4;
    acc1 += ab[s + 5] * v5;
    acc0 += ab[s + 6] * v6;
    acc1 += ab[s + 7] * v7;
  }
  *(f32x4*)(part + (size_t)(b * 32 + sc) * ND + tid * 4) = acc0 + acc1;
}

__global__ __launch_bounds__(256) void k_ctx_red(const float* __restrict__ part,
                                                 float* __restrict__ ctx, int count) {
  const int b = blockIdx.x, tid = threadIdx.x;
  f32x4 acc = (f32x4){0.f, 0.f, 0.f, 0.f};
  for (int sc = 0; sc < count; ++sc)
    acc += *(const f32x4*)(part + (size_t)(b * count + sc) * ND + tid * 4);
  *(f32x4*)(ctx + (size_t)b * ND + tid * 4) = acc;
}

extern "C" void kernel_launch(void* const* d_in, const int* in_sizes, int n_in,
                              void* d_out, int out_size, void* d_ws, size_t ws_size,
                              hipStream_t stream) {
  const float* query  = (const float*)d_in[0];
  const float* values = (const float*)d_in[1];
  const float* W1     = (const float*)d_in[2];
  const float* b1     = (const float*)d_in[3];
  const float* W2     = (const float*)d_in[4];
  const float* b2     = (const float*)d_in[5];
  const float* V      = (const float*)d_in[6];
  // d_in[7] = bV: uniform score shift -> cancels in softmax.

  float* ctx  = (float*)d_out;
  float* attn = (float*)d_out + NB * ND;

  char* ws = (char*)d_ws;
  const size_t SZ_VALH = (size_t)NM * ND * 2;  // 128 MiB
  const size_t need_h = SZ_VALH + 2097152 + 524288 + 131072 + 262144 + 8388608;

  if (ws_size >= need_h) {
    _Float16* valh   = (_Float16*)ws;
    _Float16* W1Th   = (_Float16*)(ws + SZ_VALH);
    float* pq_part   = (float*)(ws + SZ_VALH + 2097152);
    float* pq        = (float*)(ws + SZ_VALH + 2621440);
    float* score     = (float*)(ws + SZ_VALH + 2752512);
    float* part      = (float*)(ws + SZ_VALH + 3014656);

    hipMemsetAsync(score, 0, NM * sizeof(float), stream);
    k_cvt<<<4096, 256, 0, stream>>>(values, valh);
    k_w1t_h<<<dim3(16, 16), 256, 0, stream>>>(W1, W1Th);
    k_pq<<<dim3(4, NB), 256, 0, stream>>>(query, W2, pq_part);
    k_pq_red<<<NB, 256, 0, stream>>>(pq_part, b1, b2, pq);
    k_score_h<<<4096, 256, 0, stream>>>(valh, W1Th, pq, V, score);
    k_softmax<<<NB, 256, 0, stream>>>(score, attn);
    k_ctx_part_h<<<dim3(64, NB), 128, 0, stream>>>(valh, attn, part);
    k_ctx_red<<<NB, 256, 0, stream>>>(part, ctx, 64);
  } else {
    unsigned short* W1T = (unsigned short*)ws;
    float* pq_part = (float*)(ws + 2097152);
    float* pq      = (float*)(ws + 2621440);
    float* score   = (float*)(ws + 2752512);
    float* part    = (float*)(ws + 3014656);

    hipMemsetAsync(score, 0, NM * sizeof(float), stream);
    k_w1t<<<dim3(16, 16), 256, 0, stream>>>(W1, W1T);
    k_pq<<<dim3(4, NB), 256, 0, stream>>>(query, W2, pq_part);
    k_pq_red<<<NB, 256, 0, stream>>>(pq_part, b1, b2, pq);
    k_score_f32<<<4096, 256, 0, stream>>>(values, W1T, pq, V, score);
    k_softmax<<<NB, 256, 0, stream>>>(score, attn);
    k_ctx_part_f32<<<dim3(32, NB), 256, 0, stream>>>(values, attn, part);
    k_ctx_red<<<NB, 256, 0, stream>>>(part, ctx, 32);
  }
}